// Round 15
// baseline (46.018 us; speedup 1.0000x reference)
//
#include <hip/hip_runtime.h>
#include <hip/hip_bf16.h>

#define IN_DIM  8192
#define OUT_DIM 16384
#define BATCH   2048
#define NG      16
#define RROWS   2     // rows per block, packed 2x bf16 per LDS u32 word
#define TPB     512
#define NITER   (OUT_DIM / 4 / TPB)   // 8

typedef float        f32x4 __attribute__((ext_vector_type(4)));
typedef unsigned int u32x4 __attribute__((ext_vector_type(4)));

// ---------------------------------------------------------------------------
// Gate mixture is linear in {a*b, a, b, 1}: out = w_ab*ab + w_a*a + w_b*b + w_c.
// ws layout (SoA): [w_ab | w_a | w_b | w_c] (4*OUT_DIM f32), then packed
// indices (OUT_DIM u32: a_idx | b_idx<<16).
// Config: RROWS=2 bf16x2-packed LDS = 32 KB -> 4 blocks/CU, 32 waves/CU
// (100% occupancy), single staging pass, NT stores (A/B-proven), one u32
// gather serves both rows' outputs.
// ---------------------------------------------------------------------------

__device__ __forceinline__ void collapse_weights(const float* __restrict__ l,
                                                 float& w_ab, float& w_a,
                                                 float& w_b, float& w_c) {
    float v[NG];
    float m = -1e30f;
#pragma unroll
    for (int k = 0; k < NG; ++k) { v[k] = l[k]; m = fmaxf(m, v[k]); }
    float s = 0.f;
#pragma unroll
    for (int k = 0; k < NG; ++k) { v[k] = __expf(v[k] - m); s += v[k]; }
    float inv = 1.0f / s;
#pragma unroll
    for (int k = 0; k < NG; ++k) v[k] *= inv;
    w_ab = v[1] - v[2] - v[4] - 2.f * v[6] - v[7] + v[8] + 2.f * v[9]
         + v[11] + v[13] - v[14];
    w_a  = v[2] + v[3] + v[6] + v[7] - v[8] - v[9] - v[12] - v[13];
    w_b  = v[4] + v[5] + v[6] + v[7] - v[8] - v[9] - v[10] - v[11];
    w_c  = v[8] + v[9] + v[10] + v[11] + v[12] + v[13] + v[14] + v[15];
}

// Kernel 1: per-column softmax -> SoA coefficients + packed u16 index pairs.
// 256 blocks x 64 threads so all CUs participate.
__global__ __launch_bounds__(64) void gate_weights_kernel(
    const float* __restrict__ logits,
    const int* __restrict__ a_idx, const int* __restrict__ b_idx,
    float* __restrict__ ws) {
    int j = blockIdx.x * blockDim.x + threadIdx.x;
    if (j >= OUT_DIM) return;
    float w_ab, w_a, w_b, w_c;
    collapse_weights(logits + (size_t)j * NG, w_ab, w_a, w_b, w_c);
    ws[j]               = w_ab;
    ws[j +     OUT_DIM] = w_a;
    ws[j + 2 * OUT_DIM] = w_b;
    ws[j + 3 * OUT_DIM] = w_c;
    unsigned int* pk = (unsigned int*)(ws + 4 * OUT_DIM);
    pk[j] = (unsigned int)a_idx[j] | ((unsigned int)b_idx[j] << 16);
}

__device__ __forceinline__ float bf16_hi_to_f(unsigned int u) {
    union { unsigned int i; float f; } c; c.i = u & 0xFFFF0000u; return c.f;
}
__device__ __forceinline__ float bf16_lo_to_f(unsigned int u) {
    union { unsigned int i; float f; } c; c.i = u << 16; return c.f;
}
__device__ __forceinline__ unsigned int pack2(float a, float b) {
    return (unsigned int)__bfloat16_as_ushort(__float2bfloat16(a))
         | ((unsigned int)__bfloat16_as_ushort(__float2bfloat16(b)) << 16);
}

// Kernel 2: grid = BATCH/RROWS = 1024, TPB=512, 32 KB LDS, 4 blocks/CU.
__global__ __launch_bounds__(TPB, 8) void gate_eval_kernel(
    const float* __restrict__ x,
    const float* __restrict__ ws,
    f32x4* __restrict__ out4) {
    __shared__ unsigned int buf[IN_DIM];           // 32 KB
    const int i0 = blockIdx.x * RROWS;

    const f32x4* wab4 = (const f32x4*)(ws);
    const f32x4* wa4  = (const f32x4*)(ws + OUT_DIM);
    const f32x4* wb4  = (const f32x4*)(ws + 2 * OUT_DIM);
    const f32x4* wc4  = (const f32x4*)(ws + 3 * OUT_DIM);
    const u32x4* pk4  = (const u32x4*)(ws + 4 * OUT_DIM);

    // Prefetch iter-0 table BEFORE staging (in flight during staging loads).
    u32x4 pkb[2];
    f32x4 wabb[2], wab_[2], wbb[2], wcb[2];
    {
        int j4 = threadIdx.x;
        pkb[0]  = pk4[j4];
        wabb[0] = wab4[j4];
        wab_[0] = wa4[j4];
        wbb[0]  = wb4[j4];
        wcb[0]  = wc4[j4];
    }

    // Stage row-pair, bf16x2-packed (f32x4 loads from both rows).
    const f32x4* xr0 = (const f32x4*)(x + (size_t)i0 * IN_DIM);
    const f32x4* xr1 = (const f32x4*)(x + (size_t)(i0 + 1) * IN_DIM);
#pragma unroll
    for (int t = 0; t < IN_DIM / 4 / TPB; ++t) {   // 4 iters
        int m = threadIdx.x + t * TPB;             // f32x4-chunk index
        f32x4 r0 = xr0[m];
        f32x4 r1 = xr1[m];
#pragma unroll
        for (int c = 0; c < 4; ++c)
            buf[m * 4 + c] = pack2(r0[c], r1[c]);
    }
    __syncthreads();

    f32x4* o0 = out4 + (size_t)i0 * (OUT_DIM / 4);
    f32x4* o1 = o0 + (OUT_DIM / 4);

#pragma unroll
    for (int k = 0; k < NITER; ++k) {              // 8, fully unrolled
        const int cur = k & 1, nxt = cur ^ 1;
        if (k + 1 < NITER) {                       // prefetch next table
            int j4n = threadIdx.x + (k + 1) * TPB;
            pkb[nxt]  = pk4[j4n];
            wabb[nxt] = wab4[j4n];
            wab_[nxt] = wa4[j4n];
            wbb[nxt]  = wb4[j4n];
            wcb[nxt]  = wc4[j4n];
        }
        int j4 = threadIdx.x + k * TPB;
        u32x4 pk = pkb[cur];
        f32x4 wab = wabb[cur], wa = wab_[cur], wb = wbb[cur], wc = wcb[cur];
        f32x4 r0, r1;
#pragma unroll
        for (int c = 0; c < 4; ++c) {
            unsigned int va = buf[pk[c] & 0xFFFFu];
            unsigned int vb = buf[pk[c] >> 16];
            float a0 = bf16_lo_to_f(va), a1 = bf16_hi_to_f(va);
            float b0 = bf16_lo_to_f(vb), b1 = bf16_hi_to_f(vb);
            r0[c] = fmaf(wab[c], a0 * b0, fmaf(wa[c], a0, fmaf(wb[c], b0, wc[c])));
            r1[c] = fmaf(wab[c], a1 * b1, fmaf(wa[c], a1, fmaf(wb[c], b1, wc[c])));
        }
        __builtin_nontemporal_store(r0, &o0[j4]);
        __builtin_nontemporal_store(r1, &o1[j4]);
    }
}

// Fallback if ws_size is too small: recompute softmax inline per column.
__global__ __launch_bounds__(256) void gate_eval_fused_kernel(
    const float* __restrict__ x,
    const float* __restrict__ logits,
    const int* __restrict__ a_idx,
    const int* __restrict__ b_idx,
    float* __restrict__ out) {
    __shared__ float row[IN_DIM];
    const int i = blockIdx.x;
    const f32x4* xr = (const f32x4*)(x + (size_t)i * IN_DIM);
    f32x4* rv = (f32x4*)row;
#pragma unroll
    for (int t = 0; t < IN_DIM / 4 / 256; ++t)
        rv[threadIdx.x + t * 256] = xr[threadIdx.x + t * 256];
    __syncthreads();
    float* o = out + (size_t)i * OUT_DIM;
    for (int k = 0; k < OUT_DIM / 256; ++k) {
        int j = threadIdx.x + k * 256;
        float w_ab, w_a, w_b, w_c;
        collapse_weights(logits + (size_t)j * NG, w_ab, w_a, w_b, w_c);
        float a = row[a_idx[j]], b = row[b_idx[j]];
        o[j] = fmaf(w_ab, a * b, fmaf(w_a, a, fmaf(w_b, b, w_c)));
    }
}

extern "C" void kernel_launch(void* const* d_in, const int* in_sizes, int n_in,
                              void* d_out, int out_size, void* d_ws, size_t ws_size,
                              hipStream_t stream) {
    const float* x      = (const float*)d_in[0];
    const float* logits = (const float*)d_in[1];
    const int*   a_idx  = (const int*)d_in[2];
    const int*   b_idx  = (const int*)d_in[3];
    float* out = (float*)d_out;

    const size_t ws_need = (size_t)(4 * OUT_DIM) * sizeof(float)
                         + (size_t)OUT_DIM * sizeof(unsigned int);  // 320 KB
    if (ws_size >= ws_need && d_ws != nullptr) {
        float* ws = (float*)d_ws;
        gate_weights_kernel<<<OUT_DIM / 64, 64, 0, stream>>>(
            logits, a_idx, b_idx, ws);
        gate_eval_kernel<<<BATCH / RROWS, TPB, 0, stream>>>(
            x, ws, (f32x4*)out);
    } else {
        gate_eval_fused_kernel<<<BATCH, 256, 0, stream>>>(
            x, logits, a_idx, b_idx, out);
    }
}

// Round 16
// 40.029 us; speedup vs baseline: 1.1496x; 1.1496x over previous
//
#include <hip/hip_runtime.h>
#include <hip/hip_bf16.h>

#define IN_DIM  8192
#define OUT_DIM 16384
#define BATCH   2048
#define NG      16
#define RROWS   2     // batch rows per block, interleaved f32x2 in LDS
#define TPB     512
#define NITER   (OUT_DIM / 4 / TPB)   // 8

typedef float        f32x2 __attribute__((ext_vector_type(2)));
typedef float        f32x4 __attribute__((ext_vector_type(4)));
typedef unsigned int u32x4 __attribute__((ext_vector_type(4)));

// ---------------------------------------------------------------------------
// Gate mixture is linear in {a*b, a, b, 1}: out = w_ab*ab + w_a*a + w_b*b + w_c.
// ws layout (SoA): [w_ab | w_a | w_b | w_c] (4*OUT_DIM f32), then packed
// indices (OUT_DIM u32: a_idx | b_idx<<16).
// BEST MEASURED STRUCTURE (round 8, 40.0 us): rows 2i,2i+1 interleaved as
// float2 in LDS (64 KB, 2 blocks/CU, grid=1024 -> 2 natural cohorts); one
// ds_read_b64 per operand serves both rows; single staging pass; table
// double-buffered in registers; NT stores (A/B-proven vs plain, R14).
// Probed and rejected: 1 blk/CU (R9 -4.2us), bf16 pack (R10/R15 null/-6),
// coop grid fusion (R11 -59), in-block dbuf (R12 null), cohort split with
// duplicate staging (R13 -15), plain stores (R14 -1.7).
// ---------------------------------------------------------------------------

__device__ __forceinline__ void collapse_weights(const float* __restrict__ l,
                                                 float& w_ab, float& w_a,
                                                 float& w_b, float& w_c) {
    float v[NG];
    float m = -1e30f;
#pragma unroll
    for (int k = 0; k < NG; ++k) { v[k] = l[k]; m = fmaxf(m, v[k]); }
    float s = 0.f;
#pragma unroll
    for (int k = 0; k < NG; ++k) { v[k] = __expf(v[k] - m); s += v[k]; }
    float inv = 1.0f / s;
#pragma unroll
    for (int k = 0; k < NG; ++k) v[k] *= inv;
    w_ab = v[1] - v[2] - v[4] - 2.f * v[6] - v[7] + v[8] + 2.f * v[9]
         + v[11] + v[13] - v[14];
    w_a  = v[2] + v[3] + v[6] + v[7] - v[8] - v[9] - v[12] - v[13];
    w_b  = v[4] + v[5] + v[6] + v[7] - v[8] - v[9] - v[10] - v[11];
    w_c  = v[8] + v[9] + v[10] + v[11] + v[12] + v[13] + v[14] + v[15];
}

// Kernel 1: per-column softmax -> SoA coefficients + packed u16 index pairs.
// 256 blocks x 64 threads so all CUs participate.
__global__ __launch_bounds__(64) void gate_weights_kernel(
    const float* __restrict__ logits,
    const int* __restrict__ a_idx, const int* __restrict__ b_idx,
    float* __restrict__ ws) {
    int j = blockIdx.x * blockDim.x + threadIdx.x;
    if (j >= OUT_DIM) return;
    float w_ab, w_a, w_b, w_c;
    collapse_weights(logits + (size_t)j * NG, w_ab, w_a, w_b, w_c);
    ws[j]               = w_ab;
    ws[j +     OUT_DIM] = w_a;
    ws[j + 2 * OUT_DIM] = w_b;
    ws[j + 3 * OUT_DIM] = w_c;
    unsigned int* pk = (unsigned int*)(ws + 4 * OUT_DIM);
    pk[j] = (unsigned int)a_idx[j] | ((unsigned int)b_idx[j] << 16);
}

// Kernel 2: grid = BATCH/RROWS = 1024, TPB=512, 64 KB LDS (2 blocks/CU).
__global__ __launch_bounds__(TPB, 4) void gate_eval_kernel(
    const float* __restrict__ x,
    const float* __restrict__ ws,
    f32x4* __restrict__ out4) {
    __shared__ f32x2 rows2[IN_DIM];                // 64 KB
    const int i0 = blockIdx.x * RROWS;

    const f32x4* wab4 = (const f32x4*)(ws);
    const f32x4* wa4  = (const f32x4*)(ws + OUT_DIM);
    const f32x4* wb4  = (const f32x4*)(ws + 2 * OUT_DIM);
    const f32x4* wc4  = (const f32x4*)(ws + 3 * OUT_DIM);
    const u32x4* pk4  = (const u32x4*)(ws + 4 * OUT_DIM);

    // Prefetch iter-0 table BEFORE staging (in flight during staging loads).
    u32x4 pkb[2];
    f32x4 wabb[2], wab_[2], wbb[2], wcb[2];
    {
        int j4 = threadIdx.x;
        pkb[0]  = pk4[j4];
        wabb[0] = wab4[j4];
        wab_[0] = wa4[j4];
        wbb[0]  = wb4[j4];
        wcb[0]  = wc4[j4];
    }

    // Stage + interleave: f32x4 loads from both rows, write float2 pairs.
    const f32x4* xr0 = (const f32x4*)(x + (size_t)i0 * IN_DIM);
    const f32x4* xr1 = (const f32x4*)(x + (size_t)(i0 + 1) * IN_DIM);
#pragma unroll
    for (int t = 0; t < IN_DIM / 4 / TPB; ++t) {   // 4 iters
        int m = threadIdx.x + t * TPB;             // f32x4-chunk index
        f32x4 r0 = xr0[m];
        f32x4 r1 = xr1[m];
#pragma unroll
        for (int c = 0; c < 4; ++c) {
            f32x2 p; p.x = r0[c]; p.y = r1[c];
            rows2[m * 4 + c] = p;
        }
    }
    __syncthreads();

    f32x4* o0 = out4 + (size_t)i0 * (OUT_DIM / 4);
    f32x4* o1 = o0 + (OUT_DIM / 4);

#pragma unroll
    for (int k = 0; k < NITER; ++k) {              // 8, fully unrolled
        const int cur = k & 1, nxt = cur ^ 1;
        if (k + 1 < NITER) {                       // prefetch next table
            int j4n = threadIdx.x + (k + 1) * TPB;
            pkb[nxt]  = pk4[j4n];
            wabb[nxt] = wab4[j4n];
            wab_[nxt] = wa4[j4n];
            wbb[nxt]  = wb4[j4n];
            wcb[nxt]  = wc4[j4n];
        }
        int j4 = threadIdx.x + k * TPB;
        u32x4 pk = pkb[cur];
        f32x4 wab = wabb[cur], wa = wab_[cur], wb = wbb[cur], wc = wcb[cur];
        f32x4 r0, r1;
#pragma unroll
        for (int c = 0; c < 4; ++c) {
            f32x2 va = rows2[pk[c] & 0xFFFFu];     // {row0[ia], row1[ia]}
            f32x2 vb = rows2[pk[c] >> 16];         // {row0[ib], row1[ib]}
            r0[c] = fmaf(wab[c], va.x * vb.x,
                         fmaf(wa[c], va.x, fmaf(wb[c], vb.x, wc[c])));
            r1[c] = fmaf(wab[c], va.y * vb.y,
                         fmaf(wa[c], va.y, fmaf(wb[c], vb.y, wc[c])));
        }
        __builtin_nontemporal_store(r0, &o0[j4]);
        __builtin_nontemporal_store(r1, &o1[j4]);
    }
}

// Fallback if ws_size is too small: recompute softmax inline per column.
__global__ __launch_bounds__(256) void gate_eval_fused_kernel(
    const float* __restrict__ x,
    const float* __restrict__ logits,
    const int* __restrict__ a_idx,
    const int* __restrict__ b_idx,
    float* __restrict__ out) {
    __shared__ float row[IN_DIM];
    const int i = blockIdx.x;
    const f32x4* xr = (const f32x4*)(x + (size_t)i * IN_DIM);
    f32x4* rv = (f32x4*)row;
#pragma unroll
    for (int t = 0; t < IN_DIM / 4 / 256; ++t)
        rv[threadIdx.x + t * 256] = xr[threadIdx.x + t * 256];
    __syncthreads();
    float* o = out + (size_t)i * OUT_DIM;
    for (int k = 0; k < OUT_DIM / 256; ++k) {
        int j = threadIdx.x + k * 256;
        float w_ab, w_a, w_b, w_c;
        collapse_weights(logits + (size_t)j * NG, w_ab, w_a, w_b, w_c);
        float a = row[a_idx[j]], b = row[b_idx[j]];
        o[j] = fmaf(w_ab, a * b, fmaf(w_a, a, fmaf(w_b, b, w_c)));
    }
}

extern "C" void kernel_launch(void* const* d_in, const int* in_sizes, int n_in,
                              void* d_out, int out_size, void* d_ws, size_t ws_size,
                              hipStream_t stream) {
    const float* x      = (const float*)d_in[0];
    const float* logits = (const float*)d_in[1];
    const int*   a_idx  = (const int*)d_in[2];
    const int*   b_idx  = (const int*)d_in[3];
    float* out = (float*)d_out;

    const size_t ws_need = (size_t)(4 * OUT_DIM) * sizeof(float)
                         + (size_t)OUT_DIM * sizeof(unsigned int);  // 320 KB
    if (ws_size >= ws_need && d_ws != nullptr) {
        float* ws = (float*)d_ws;
        gate_weights_kernel<<<OUT_DIM / 64, 64, 0, stream>>>(
            logits, a_idx, b_idx, ws);
        gate_eval_kernel<<<BATCH / RROWS, TPB, 0, stream>>>(
            x, ws, (f32x4*)out);
    } else {
        gate_eval_fused_kernel<<<BATCH, 256, 0, stream>>>(
            x, logits, a_idx, b_idx, out);
    }
}